// Round 7
// baseline (983.761 us; speedup 1.0000x reference)
//
#include <hip/hip_runtime.h>
#include <hip/hip_bf16.h>
#include <hip/hip_cooperative_groups.h>

namespace cg = cooperative_groups;

typedef __attribute__((ext_vector_type(8))) short bf16x8;
typedef __attribute__((ext_vector_type(4))) float f32x4;
typedef __attribute__((ext_vector_type(8))) unsigned short u16x8;
typedef unsigned short ushort_t;
typedef unsigned int u32;

__device__ __forceinline__ ushort_t f2b(float f) {
    u32 u = __builtin_bit_cast(u32, f);
    u += 0x7FFFu + ((u >> 16) & 1u);
    return (ushort_t)(u >> 16);
}

__device__ __forceinline__ void gload_lds16(const void* g, void* l) {
    __builtin_amdgcn_global_load_lds(
        (const __attribute__((address_space(1))) u32*)g,
        (__attribute__((address_space(3))) u32*)l, 16, 0, 0);
}

struct TrDesc { const float* src; ushort_t* dst; int K, N, Kpad, Npad, base, nx; };

struct CoopArgs {
    TrDesc d[6];
    const float* low; const int* lbl; const float* emb;
    const float *b1, *b2, *b3, *b4, *b5;
    ushort_t *xb, *h1, *h2, *fc, *h4, *h5;
    ushort_t *w1t, *w2t, *w3t, *w4t, *w5t;
    int trbase, total0;
};

// ---- verified 64x64 dbuf GEMM tile as device fn (smem: As=base, Bs=base+8192) --
template<int RELU>
__device__ __forceinline__ void tile_gemm64(
    const ushort_t* __restrict__ A, const ushort_t* __restrict__ Bt,
    const float* __restrict__ bias, ushort_t* __restrict__ Cb,
    int K, int Nreal, int ldc, int m0, int n0, char* smem, int tid)
{
    ushort_t* As = (ushort_t*)smem;
    ushort_t* Bs = (ushort_t*)(smem + 8192);
    const int wave = tid >> 6, lane = tid & 63;
    const int l15 = lane & 15, g = lane >> 4;
    const int wr = wave >> 1, wc = wave & 1;

    f32x4 acc[2][2] = {};

    const int p0 = tid * 16;
    const int row0 = p0 >> 6;
    const int k0s = (((p0 & 63) ^ (((row0 >> 1) & 3) << 4)) >> 1);
    const ushort_t* a0 = A + (size_t)(m0 + row0) * K + k0s;
    const ushort_t* b0 = Bt + (size_t)(n0 + row0) * K + k0s;

    char* AsB = smem + wave * 1024;
    char* BsB = smem + 8192 + wave * 1024;

    const int sxor = ((l15 >> 1) & 3) << 4;
    const ushort_t* ardA = As + (((wr * 32 + l15) * 64 + ((g * 16) ^ sxor)) >> 1);
    const ushort_t* brdB = Bs + (((wc * 32 + l15) * 64 + ((g * 16) ^ sxor)) >> 1);

    const int nk = K >> 5;
    gload_lds16(a0, AsB); gload_lds16(b0, BsB);
    a0 += 32; b0 += 32;
    __syncthreads();
    for (int kk = 0; kk < nk; ++kk) {
        const int cur = kk & 1, nxt = cur ^ 1;
        if (kk + 1 < nk) {
            gload_lds16(a0, AsB + nxt * 4096);
            gload_lds16(b0, BsB + nxt * 4096);
            a0 += 32; b0 += 32;
        }
        bf16x8 af[2], bf[2];
        #pragma unroll
        for (int i = 0; i < 2; ++i) af[i] = *(const bf16x8*)(ardA + cur * 2048 + i * 512);
        #pragma unroll
        for (int j = 0; j < 2; ++j) bf[j] = *(const bf16x8*)(brdB + cur * 2048 + j * 512);
        #pragma unroll
        for (int i = 0; i < 2; ++i)
            #pragma unroll
            for (int j = 0; j < 2; ++j)
                acc[i][j] = __builtin_amdgcn_mfma_f32_16x16x32_bf16(af[i], bf[j], acc[i][j], 0, 0, 0);
        __syncthreads();
    }

    #pragma unroll
    for (int i = 0; i < 2; ++i)
        #pragma unroll
        for (int r = 0; r < 4; ++r) {
            int row = m0 + wr * 32 + i * 16 + g * 4 + r;
            #pragma unroll
            for (int j = 0; j < 2; ++j) {
                int col = n0 + wc * 32 + j * 16 + l15;
                if (col >= Nreal) continue;
                float v = acc[i][j][r] + bias[col];
                if (RELU) v = fmaxf(v, 0.f);
                Cb[(size_t)row * ldc + col] = f2b(v);
            }
        }
}

// ---- cooperative mega-kernel: prep -> L1 -> L2 -> L3+emb -> L4 -> L5 ----------
__global__ __launch_bounds__(256) void coop_chain(CoopArgs a) {
    __shared__ __align__(16) char smem[16640];   // max(T 64x65 f32, 2x dbuf 8KB)
    const int tid = threadIdx.x;
    const int bid = blockIdx.x;
    const int nb = gridDim.x;
    cg::grid_group grid = cg::this_grid();

    // ---- phase 0: weight transpose-casts + x cast-pad ----
    for (int u = bid; u < a.total0; u += nb) {
        if (u < a.trbase) {
            float (*T)[65] = (float(*)[65])smem;
            int w = 0;
            #pragma unroll
            for (int i = 1; i < 6; ++i) if (u >= a.d[i].base) w = i;
            const TrDesc d = a.d[w];
            const int local = u - d.base;
            const int n0 = (local % d.nx) * 64, k0 = (local / d.nx) * 64;
            #pragma unroll
            for (int it = 0; it < 16; ++it) {
                int idx = it * 256 + tid;
                int r = idx >> 6, c = idx & 63;
                int k = k0 + r, n = n0 + c;
                T[c][r] = (k < d.K && n < d.N) ? d.src[(size_t)k * d.N + n] : 0.f;
            }
            __syncthreads();
            #pragma unroll
            for (int it = 0; it < 16; ++it) {
                int idx = it * 256 + tid;
                int r = idx >> 6, c = idx & 63;
                int n = n0 + r, k = k0 + c;
                if (k < d.Kpad)
                    d.dst[(size_t)n * d.Kpad + k] = f2b(T[r][c]);
            }
            __syncthreads();
        } else {
            int idx = (u - a.trbase) * 256 + tid;     // 0..311295
            int b = idx / 76, c = idx - b * 76;
            ushort_t* dp = a.xb + (size_t)b * 608 + c * 8;
            u16x8 o;
            if (c < 75) {
                const float* sp = a.low + (size_t)b * 600 + c * 8;
                f32x4 v0 = *(const f32x4*)sp, v1 = *(const f32x4*)(sp + 4);
                #pragma unroll
                for (int j = 0; j < 4; ++j) { o[j] = f2b(v0[j]); o[4 + j] = f2b(v1[j]); }
            } else {
                #pragma unroll
                for (int j = 0; j < 8; ++j) o[j] = 0;
            }
            *(u16x8*)dp = o;
            __syncthreads();
        }
    }
    __threadfence();
    grid.sync();

    // ---- L1: xb(608) @ w1t -> h1(512) relu; 512 tiles (nx=8) ----
    for (int t = bid; t < 512; t += nb)
        tile_gemm64<1>(a.xb, a.w1t, a.b1, a.h1, 608, 512, 512, (t >> 3) * 64, (t & 7) * 64, smem, tid);
    __threadfence();
    grid.sync();

    // ---- L2: h1(512) @ w2t -> h2(256) relu; 256 tiles (nx=4) ----
    for (int t = bid; t < 256; t += nb)
        tile_gemm64<1>(a.h1, a.w2t, a.b2, a.h2, 512, 256, 256, (t >> 2) * 64, (t & 3) * 64, smem, tid);
    __threadfence();
    grid.sync();

    // ---- L3: h2(256) @ w3t -> fc[:,0:128] (ldc=160); 128 tiles (nx=2) + emb ----
    for (int t = bid; t < 128; t += nb)
        tile_gemm64<0>(a.h2, a.w3t, a.b3, a.fc, 256, 128, 160, (t >> 1) * 64, (t & 1) * 64, smem, tid);
    for (int u = bid; u < 512; u += nb) {
        int e = u * 256 + tid;                // 4096*32 elems
        int row = e >> 5, c = e & 31;
        float v = c < 16 ? a.emb[(size_t)a.lbl[row] * 16 + c] : 0.f;
        a.fc[(size_t)row * 160 + 128 + c] = f2b(v);
    }
    __threadfence();
    grid.sync();

    // ---- L4: fc(160) @ w4t -> h4(256) relu; 256 tiles (nx=4) ----
    for (int t = bid; t < 256; t += nb)
        tile_gemm64<1>(a.fc, a.w4t, a.b4, a.h4, 160, 256, 256, (t >> 2) * 64, (t & 3) * 64, smem, tid);
    __threadfence();
    grid.sync();

    // ---- L5: h4(256) @ w5t -> h5(512) relu; 512 tiles (nx=8) ----
    for (int t = bid; t < 512; t += nb)
        tile_gemm64<1>(a.h4, a.w5t, a.b5, a.h5, 256, 512, 512, (t >> 3) * 64, (t & 7) * 64, smem, tid);
}

// ---- L6: 256x256 tile, 512 threads / 8 waves, dbuf, fused epilogue ------------
__global__ __launch_bounds__(512) void gemm256_l6(
    const ushort_t* __restrict__ A, const ushort_t* __restrict__ Bt,
    const float* __restrict__ bias, float* __restrict__ Cf,
    const float* __restrict__ low, int K)
{
    __shared__ ushort_t As[2][256 * 32];   // 16KB per buf
    __shared__ ushort_t Bs[2][256 * 32];
    const int tid = threadIdx.x;
    const int wave = tid >> 6, lane = tid & 63;
    const int l15 = lane & 15, g = lane >> 4;
    const int wr = wave >> 2, wc = wave & 3;        // 2 x 4 wave grid
    const int m0 = blockIdx.y * 256, n0 = blockIdx.x * 256;

    f32x4 acc[8][4] = {};

    const int p0 = tid * 16;
    const int row0 = p0 >> 6;                        // 0..127
    const int k0s = (((p0 & 63) ^ (((row0 >> 1) & 3) << 4)) >> 1);
    const int p1 = 8192 + tid * 16;
    const int row1 = p1 >> 6;                        // 128..255
    const int k1s = (((p1 & 63) ^ (((row1 >> 1) & 3) << 4)) >> 1);

    const ushort_t* a0 = A + (size_t)(m0 + row0) * K + k0s;
    const ushort_t* a1 = A + (size_t)(m0 + row1) * K + k1s;
    const ushort_t* b0 = Bt + (size_t)(n0 + row0) * K + k0s;
    const ushort_t* b1 = Bt + (size_t)(n0 + row1) * K + k1s;

    char* AsB = (char*)As + wave * 1024;
    char* BsB = (char*)Bs + wave * 1024;

    const int sxor = ((l15 >> 1) & 3) << 4;
    const ushort_t* ardA = &As[0][0] + (((wr * 128 + l15) * 64 + ((g * 16) ^ sxor)) >> 1);
    const ushort_t* brdB = &Bs[0][0] + (((wc * 64 + l15) * 64 + ((g * 16) ^ sxor)) >> 1);

    const int nk = K >> 5;   // 16
    gload_lds16(a0, AsB); gload_lds16(a1, AsB + 8192);
    gload_lds16(b0, BsB); gload_lds16(b1, BsB + 8192);
    a0 += 32; a1 += 32; b0 += 32; b1 += 32;
    __syncthreads();
    for (int kk = 0; kk < nk; ++kk) {
        const int cur = kk & 1, nxt = cur ^ 1;
        if (kk + 1 < nk) {
            gload_lds16(a0, AsB + nxt * 16384);
            gload_lds16(a1, AsB + nxt * 16384 + 8192);
            gload_lds16(b0, BsB + nxt * 16384);
            gload_lds16(b1, BsB + nxt * 16384 + 8192);
            a0 += 32; a1 += 32; b0 += 32; b1 += 32;
        }
        bf16x8 bf[4];
        #pragma unroll
        for (int j = 0; j < 4; ++j) bf[j] = *(const bf16x8*)(brdB + cur * 8192 + j * 512);
        #pragma unroll
        for (int i = 0; i < 8; ++i) {
            bf16x8 af = *(const bf16x8*)(ardA + cur * 8192 + i * 512);
            #pragma unroll
            for (int j = 0; j < 4; ++j)
                acc[i][j] = __builtin_amdgcn_mfma_f32_16x16x32_bf16(af, bf[j], acc[i][j], 0, 0, 0);
        }
        __syncthreads();
    }

    // epilogue: per-j state; row outer, j inner (256B contiguous per wave-row)
    float bvv[4]; int offv[4]; float alphav[4];
    bool anch[4], interi[4], valid[4];
    #pragma unroll
    for (int j = 0; j < 4; ++j) {
        int col = n0 + wc * 64 + j * 16 + l15;
        valid[j] = col < 12000;
        int cc = valid[j] ? col : 0;
        bvv[j] = bias[cc];
        int t = cc / 6, f = cc - t * 6;
        int seg = t / 20; if (seg > 98) seg = 98;
        offv[j] = seg * 6 + f;
        alphav[j] = (float)(t - seg * 20) * 0.05f;
        anch[j] = (t % 20) == 0;
        interi[j] = t < 1980;
    }
    const int colb = n0 + wc * 64 + l15;
    #pragma unroll
    for (int i = 0; i < 8; ++i)
        #pragma unroll
        for (int r = 0; r < 4; ++r) {
            const int row = m0 + wr * 128 + i * 16 + g * 4 + r;
            const float* lrow = low + (size_t)row * 600;
            float* orow = Cf + (size_t)row * 12000;
            #pragma unroll
            for (int j = 0; j < 4; ++j) {
                if (!valid[j]) continue;
                float s = lrow[offv[j]], e = lrow[offv[j] + 6];
                float lin = (1.f - alphav[j]) * s + alphav[j] * e;
                float dec = acc[i][j][r] + bvv[j];
                float res = anch[j] ? lin : (interi[j] ? lin + 0.2f * (dec - lin) : dec);
                orow[colb + j * 16] = res;
            }
        }
}

extern "C" void kernel_launch(void* const* d_in, const int* in_sizes, int n_in,
                              void* d_out, int out_size, void* d_ws, size_t ws_size,
                              hipStream_t stream) {
    const float* low = (const float*)d_in[0];
    const int*   lbl = (const int*)d_in[1];
    const float* W1 = (const float*)d_in[2];  const float* b1 = (const float*)d_in[3];
    const float* W2 = (const float*)d_in[4];  const float* b2 = (const float*)d_in[5];
    const float* W3 = (const float*)d_in[6];  const float* b3 = (const float*)d_in[7];
    const float* W4 = (const float*)d_in[8];  const float* b4 = (const float*)d_in[9];
    const float* W5 = (const float*)d_in[10]; const float* b5 = (const float*)d_in[11];
    const float* W6 = (const float*)d_in[12]; const float* b6 = (const float*)d_in[13];
    const float* emb = (const float*)d_in[14];
    float* out = (float*)d_out;

    char* ws = (char*)d_ws;
    size_t off = 0;
    auto alloc = [&](size_t elems) {
        ushort_t* p = (ushort_t*)(ws + off);
        off = (off + elems * 2 + 255) & ~(size_t)255;
        return p;
    };
    ushort_t* xb  = alloc((size_t)4096 * 608);
    ushort_t* w1t = alloc((size_t)512 * 608);
    ushort_t* w2t = alloc((size_t)256 * 512);
    ushort_t* w3t = alloc((size_t)128 * 256);
    ushort_t* w4t = alloc((size_t)256 * 160);
    ushort_t* w5t = alloc((size_t)512 * 256);
    ushort_t* w6t = alloc((size_t)12032 * 512);
    ushort_t* h1  = alloc((size_t)4096 * 512);
    ushort_t* h2  = alloc((size_t)4096 * 256);
    ushort_t* fc  = alloc((size_t)4096 * 160);
    ushort_t* h4  = alloc((size_t)4096 * 256);
    ushort_t* h5  = alloc((size_t)4096 * 512);

    CoopArgs ca;
    int base = 0;
    auto mk = [&](int i, const float* s, ushort_t* d, int K, int N, int Kp, int Np) {
        int nx = Np / 64, ny = (Kp + 63) / 64;
        ca.d[i] = TrDesc{s, d, K, N, Kp, Np, base, nx};
        base += nx * ny;
    };
    mk(0, W1, w1t, 600, 512, 608, 512);
    mk(1, W2, w2t, 512, 256, 512, 256);
    mk(2, W3, w3t, 256, 128, 256, 128);
    mk(3, W4, w4t, 144, 256, 160, 256);
    mk(4, W5, w5t, 256, 512, 256, 512);
    mk(5, W6, w6t, 512, 12000, 512, 12032);
    ca.low = low; ca.lbl = lbl; ca.emb = emb;
    ca.b1 = b1; ca.b2 = b2; ca.b3 = b3; ca.b4 = b4; ca.b5 = b5;
    ca.xb = xb; ca.h1 = h1; ca.h2 = h2; ca.fc = fc; ca.h4 = h4; ca.h5 = h5;
    ca.w1t = w1t; ca.w2t = w2t; ca.w3t = w3t; ca.w4t = w4t; ca.w5t = w5t;
    ca.trbase = base;
    ca.total0 = base + (4096 * 76) / 256;   // + 1216 cast-x units

    void* kp[] = { (void*)&ca };
    hipLaunchCooperativeKernel((void*)coop_chain, dim3(512), dim3(256), kp, 0, stream);

    // L6: h5(512) @ w6t + fused interp/blend -> out f32   [47 x 16 blocks]
    gemm256_l6<<<dim3(47, 16), 512, 0, stream>>>(h5, w6t, b6, out, low, 512);
}

// Round 8
// 380.889 us; speedup vs baseline: 2.5828x; 2.5828x over previous
//
#include <hip/hip_runtime.h>
#include <hip/hip_bf16.h>

typedef __attribute__((ext_vector_type(8))) short bf16x8;
typedef __attribute__((ext_vector_type(4))) float f32x4;
typedef __attribute__((ext_vector_type(8))) unsigned short u16x8;
typedef unsigned short ushort_t;
typedef unsigned int u32;

__device__ __forceinline__ ushort_t f2b(float f) {
    u32 u = __builtin_bit_cast(u32, f);
    u += 0x7FFFu + ((u >> 16) & 1u);
    return (ushort_t)(u >> 16);
}

__device__ __forceinline__ void gload_lds16(const void* g, void* l) {
    __builtin_amdgcn_global_load_lds(
        (const __attribute__((address_space(1))) u32*)g,
        (__attribute__((address_space(3))) u32*)l, 16, 0, 0);
}

// ---------------- prep: 6x transpose-cast W [K][N] f32 -> Wt [Npad][Kpad] bf16 --
struct TrDesc { const float* src; ushort_t* dst; int K, N, Kpad, Npad, base, nx; };
struct TrArgs { TrDesc d[6]; };

__global__ __launch_bounds__(256) void prep_kernel(TrArgs a) {
    __shared__ float T[64][65];
    const int bid = blockIdx.x, tid = threadIdx.x;
    int w = 0;
    #pragma unroll
    for (int i = 1; i < 6; ++i) if (bid >= a.d[i].base) w = i;
    const TrDesc d = a.d[w];
    const int local = bid - d.base;
    const int n0 = (local % d.nx) * 64, k0 = (local / d.nx) * 64;
    #pragma unroll
    for (int it = 0; it < 16; ++it) {
        int idx = it * 256 + tid;
        int r = idx >> 6, c = idx & 63;
        int k = k0 + r, n = n0 + c;
        T[c][r] = (k < d.K && n < d.N) ? d.src[(size_t)k * d.N + n] : 0.f;
    }
    __syncthreads();
    #pragma unroll
    for (int it = 0; it < 16; ++it) {
        int idx = it * 256 + tid;
        int r = idx >> 6, c = idx & 63;
        int n = n0 + r, k = k0 + c;
        if (k < d.Kpad)
            d.dst[(size_t)n * d.Kpad + k] = f2b(T[r][c]);
    }
}

// ---------------- fused L1..L5 chain: one block = 16 rows through all layers ----
// Activations live in LDS in "chunked" layout: chunk c (32 elems) at byte
// c*1024; within: row*64 + ((2*(k&31)) ^ ((row>>1)&3)<<4)  (same XOR-swizzled
// layout the verified MFMA frag-read consumes). Weights staged via verified
// dbuf global_load_lds path (B-region: 256 rows x 32 k per step, 4 issues).
__device__ __forceinline__ void layer_run(
    const char* actIn, char* actOut, char* Bsb,
    const ushort_t* __restrict__ Wt, const float* __restrict__ bias,
    int K, int N, bool relu, int tid)
{
    const int wave = tid >> 6, lane = tid & 63;
    const int l15 = lane & 15, g = lane >> 4;
    const int row_t = tid >> 2;                       // staged row 0..63 (+i*64)
    const int sw_s = ((row_t >> 1) & 3) << 4;
    const int koff = ((((tid & 3) << 4)) ^ sw_s) >> 1;
    const int sxor = ((l15 >> 1) & 3) << 4;
    const int aRd = l15 * 64 + ((g * 16) ^ sxor);     // A-frag byte (+kk*1024)
    const int bRd = wave * 4096 + l15 * 64 + ((g * 16) ^ sxor);  // +j*1024
    char* stW = Bsb + wave * 1024;                    // wave-uniform dest base
    const int nk = K >> 5;
    const int nmt = (N + 255) >> 8;

    for (int mt = 0; mt < nmt; ++mt) {
        const int ncols = N - mt * 256;
        const ushort_t* src0 = Wt + (size_t)(mt * 256 + row_t) * K + koff;
        f32x4 acc[4] = {};
        #pragma unroll
        for (int i = 0; i < 4; ++i)
            if (i * 64 < ncols) gload_lds16(src0 + (size_t)i * 64 * K, stW + i * 4096);
        __syncthreads();
        for (int kk = 0; kk < nk; ++kk) {
            const int cur = kk & 1, nxt = cur ^ 1;
            if (kk + 1 < nk) {
                #pragma unroll
                for (int i = 0; i < 4; ++i)
                    if (i * 64 < ncols)
                        gload_lds16(src0 + (size_t)i * 64 * K + (kk + 1) * 32,
                                    stW + nxt * 16384 + i * 4096);
            }
            bf16x8 af = *(const bf16x8*)(actIn + kk * 1024 + aRd);
            #pragma unroll
            for (int j = 0; j < 4; ++j) {
                bf16x8 bf = *(const bf16x8*)(Bsb + cur * 16384 + bRd + j * 1024);
                acc[j] = __builtin_amdgcn_mfma_f32_16x16x32_bf16(af, bf, acc[j], 0, 0, 0);
            }
            __syncthreads();
        }
        // epilogue: C (m = g*4+r, n = col) -> actOut chunked-swizzled layout
        #pragma unroll
        for (int j = 0; j < 4; ++j) {
            int col = mt * 256 + wave * 64 + j * 16 + l15;
            if (col < N) {
                float bv = bias[col];
                #pragma unroll
                for (int r = 0; r < 4; ++r) {
                    float v = acc[j][r] + bv;
                    if (relu) v = fmaxf(v, 0.f);
                    int mrow = g * 4 + r;
                    int sw = ((mrow >> 1) & 3) << 4;
                    *(ushort_t*)(actOut + (col >> 5) * 1024 + mrow * 64 +
                                 ((2 * (col & 31)) ^ sw)) = f2b(v);
                }
            }
        }
    }
    __syncthreads();
}

struct ChainArgs {
    const float* low; const int* lbl; const float* emb;
    const ushort_t *w1t, *w2t, *w3t, *w4t, *w5t;
    const float *b1, *b2, *b3, *b4, *b5;
    ushort_t* h5;
};

__global__ __launch_bounds__(256) void chain_kernel(ChainArgs a) {
    __shared__ __align__(16) char smem[19456 + 16384 + 2 * 16384];
    char* act0 = smem;                 // up to 19 chunks (x: K=608)
    char* act1 = smem + 19456;         // up to 16 chunks (h1: 512)
    char* Bsb  = smem + 19456 + 16384; // weight dbuf 2 x 16KB
    const int tid = threadIdx.x;
    const int m0 = blockIdx.x << 4;

    // load x rows -> act0 chunks (bf16, swizzled), pad 600..607 = 0
    for (int u = tid; u < 1216; u += 256) {
        int row = u / 76, c8 = u - row * 76;
        int sw = ((row >> 1) & 3) << 4;
        char* dst = act0 + (c8 >> 2) * 1024 + row * 64 + ((((c8 & 3) << 4)) ^ sw);
        u16x8 o;
        if (c8 < 75) {
            const float* sp = a.low + (size_t)(m0 + row) * 600 + c8 * 8;
            f32x4 v0 = *(const f32x4*)sp, v1 = *(const f32x4*)(sp + 4);
            #pragma unroll
            for (int j = 0; j < 4; ++j) { o[j] = f2b(v0[j]); o[4 + j] = f2b(v1[j]); }
        } else {
            #pragma unroll
            for (int j = 0; j < 8; ++j) o[j] = 0;
        }
        *(u16x8*)dst = o;
    }
    __syncthreads();

    layer_run(act0, act1, Bsb, a.w1t, a.b1, 608, 512, true,  tid);
    layer_run(act1, act0, Bsb, a.w2t, a.b2, 512, 256, true,  tid);
    layer_run(act0, act1, Bsb, a.w3t, a.b3, 256, 128, false, tid);

    // label embedding -> act1 chunk 4 (cols 128..159; >=144 zero)
    for (int u = tid; u < 512; u += 256) {
        int row = u >> 5, c = u & 31;
        float v = c < 16 ? a.emb[(size_t)a.lbl[m0 + row] * 16 + c] : 0.f;
        int sw = ((row >> 1) & 3) << 4;
        *(ushort_t*)(act1 + 4096 + row * 64 + ((2 * c) ^ sw)) = f2b(v);
    }
    __syncthreads();

    layer_run(act1, act0, Bsb, a.w4t, a.b4, 160, 256, true, tid);
    layer_run(act0, act1, Bsb, a.w5t, a.b5, 256, 512, true, tid);

    // de-swizzle act1 -> h5 global [4096][512] bf16 row-major
    for (int u = tid; u < 1024; u += 256) {
        int row = u >> 6, c8 = u & 63;
        int sw = ((row >> 1) & 3) << 4;
        u16x8 v = *(const u16x8*)(act1 + (c8 >> 2) * 1024 + row * 64 +
                                  (((c8 & 3) << 4) ^ sw));
        *(u16x8*)(a.h5 + (size_t)(m0 + row) * 512 + (c8 << 3)) = v;
    }
}

// ------------- 128x128 GEMM for L6, dbuf 2-phase + fused epilogue (plain st) ---
__global__ __launch_bounds__(256, 4) void gemm128_l6(
    const ushort_t* __restrict__ A, const ushort_t* __restrict__ Bt,
    const float* __restrict__ bias, float* __restrict__ Cf,
    const float* __restrict__ low, int K)
{
    __shared__ ushort_t As[2][128 * 32];
    __shared__ ushort_t Bs[2][128 * 32];
    const int tid = threadIdx.x;
    const int wave = tid >> 6, lane = tid & 63;
    const int l15 = lane & 15, g = lane >> 4;
    const int wr = wave >> 1, wc = wave & 1;
    const int m0 = blockIdx.y * 128, n0 = blockIdx.x * 128;

    f32x4 acc[4][4] = {};

    const int p0 = tid * 16;
    const int row0 = p0 >> 6;
    const int k0s = (((p0 & 63) ^ (((row0 >> 1) & 3) << 4)) >> 1);
    const int p1 = 4096 + tid * 16;
    const int row1 = p1 >> 6;
    const int k1s = (((p1 & 63) ^ (((row1 >> 1) & 3) << 4)) >> 1);

    const ushort_t* a0 = A + (size_t)(m0 + row0) * K + k0s;
    const ushort_t* a1 = A + (size_t)(m0 + row1) * K + k1s;
    const ushort_t* b0 = Bt + (size_t)(n0 + row0) * K + k0s;
    const ushort_t* b1 = Bt + (size_t)(n0 + row1) * K + k1s;

    char* AsB = (char*)As + wave * 1024;
    char* BsB = (char*)Bs + wave * 1024;

    const int sxor = ((l15 >> 1) & 3) << 4;
    const ushort_t* ardA = &As[0][0] + (((wr * 64 + l15) * 64 + ((g * 16) ^ sxor)) >> 1);
    const ushort_t* brdB = &Bs[0][0] + (((wc * 64 + l15) * 64 + ((g * 16) ^ sxor)) >> 1);

    const int nk = K >> 5;   // 16
    gload_lds16(a0, AsB); gload_lds16(a1, AsB + 4096);
    gload_lds16(b0, BsB); gload_lds16(b1, BsB + 4096);
    a0 += 32; a1 += 32; b0 += 32; b1 += 32;
    __syncthreads();
    #pragma unroll 2
    for (int kk = 0; kk < nk; ++kk) {
        const int cur = kk & 1, nxt = cur ^ 1;
        if (kk + 1 < nk) {
            gload_lds16(a0, AsB + nxt * 8192);
            gload_lds16(a1, AsB + nxt * 8192 + 4096);
            gload_lds16(b0, BsB + nxt * 8192);
            gload_lds16(b1, BsB + nxt * 8192 + 4096);
            a0 += 32; a1 += 32; b0 += 32; b1 += 32;
        }
        bf16x8 af[4], bf[4];
        #pragma unroll
        for (int i = 0; i < 4; ++i) af[i] = *(const bf16x8*)(ardA + cur * 4096 + i * 512);
        #pragma unroll
        for (int j = 0; j < 4; ++j) bf[j] = *(const bf16x8*)(brdB + cur * 4096 + j * 512);
        #pragma unroll
        for (int i = 0; i < 4; ++i)
            #pragma unroll
            for (int j = 0; j < 4; ++j)
                acc[i][j] = __builtin_amdgcn_mfma_f32_16x16x32_bf16(af[i], bf[j], acc[i][j], 0, 0, 0);
        __syncthreads();
    }

    float bvv[4]; int offv[4]; float alphav[4];
    bool anch[4], interi[4], valid[4];
    #pragma unroll
    for (int j = 0; j < 4; ++j) {
        int col = n0 + wc * 64 + j * 16 + l15;
        valid[j] = col < 12000;
        int cc = valid[j] ? col : 0;
        bvv[j] = bias[cc];
        int t = cc / 6, f = cc - t * 6;
        int seg = t / 20; if (seg > 98) seg = 98;
        offv[j] = seg * 6 + f;
        alphav[j] = (float)(t - seg * 20) * 0.05f;
        anch[j] = (t % 20) == 0;
        interi[j] = t < 1980;
    }
    const int colb = n0 + wc * 64 + l15;
    #pragma unroll
    for (int i = 0; i < 4; ++i)
        #pragma unroll
        for (int r = 0; r < 4; ++r) {
            const int row = m0 + wr * 64 + i * 16 + g * 4 + r;
            const float* lrow = low + (size_t)row * 600;
            float* orow = Cf + (size_t)row * 12000;
            #pragma unroll
            for (int j = 0; j < 4; ++j) {
                if (!valid[j]) continue;
                float s = lrow[offv[j]], e = lrow[offv[j] + 6];
                float lin = (1.f - alphav[j]) * s + alphav[j] * e;
                float dec = acc[i][j][r] + bvv[j];
                float res = anch[j] ? lin : (interi[j] ? lin + 0.2f * (dec - lin) : dec);
                orow[colb + j * 16] = res;
            }
        }
}

extern "C" void kernel_launch(void* const* d_in, const int* in_sizes, int n_in,
                              void* d_out, int out_size, void* d_ws, size_t ws_size,
                              hipStream_t stream) {
    const float* low = (const float*)d_in[0];
    const int*   lbl = (const int*)d_in[1];
    const float* W1 = (const float*)d_in[2];  const float* b1 = (const float*)d_in[3];
    const float* W2 = (const float*)d_in[4];  const float* b2 = (const float*)d_in[5];
    const float* W3 = (const float*)d_in[6];  const float* b3 = (const float*)d_in[7];
    const float* W4 = (const float*)d_in[8];  const float* b4 = (const float*)d_in[9];
    const float* W5 = (const float*)d_in[10]; const float* b5 = (const float*)d_in[11];
    const float* W6 = (const float*)d_in[12]; const float* b6 = (const float*)d_in[13];
    const float* emb = (const float*)d_in[14];
    float* out = (float*)d_out;

    char* ws = (char*)d_ws;
    size_t off = 0;
    auto alloc = [&](size_t elems) {
        ushort_t* p = (ushort_t*)(ws + off);
        off = (off + elems * 2 + 255) & ~(size_t)255;
        return p;
    };
    ushort_t* w1t = alloc((size_t)512 * 608);
    ushort_t* w2t = alloc((size_t)256 * 512);
    ushort_t* w3t = alloc((size_t)128 * 256);
    ushort_t* w4t = alloc((size_t)256 * 160);
    ushort_t* w5t = alloc((size_t)512 * 256);
    ushort_t* w6t = alloc((size_t)12032 * 512);
    ushort_t* h5  = alloc((size_t)4096 * 512);

    TrArgs ta;
    int base = 0;
    auto mk = [&](int i, const float* s, ushort_t* d, int K, int N, int Kp, int Np) {
        int nx = Np / 64, ny = (Kp + 63) / 64;
        ta.d[i] = TrDesc{s, d, K, N, Kp, Np, base, nx};
        base += nx * ny;
    };
    mk(0, W1, w1t, 600, 512, 608, 512);
    mk(1, W2, w2t, 512, 256, 512, 256);
    mk(2, W3, w3t, 256, 128, 256, 128);
    mk(3, W4, w4t, 144, 256, 160, 256);
    mk(4, W5, w5t, 256, 512, 256, 512);
    mk(5, W6, w6t, 512, 12000, 512, 12032);

    prep_kernel<<<dim3(base), 256, 0, stream>>>(ta);

    ChainArgs ca;
    ca.low = low; ca.lbl = lbl; ca.emb = emb;
    ca.w1t = w1t; ca.w2t = w2t; ca.w3t = w3t; ca.w4t = w4t; ca.w5t = w5t;
    ca.b1 = b1; ca.b2 = b2; ca.b3 = b3; ca.b4 = b4; ca.b5 = b5;
    ca.h5 = h5;
    chain_kernel<<<dim3(256), 256, 0, stream>>>(ca);

    // L6: h5(512) @ w6t + fused interp/blend -> out f32   [94x32 blocks]
    gemm128_l6<<<dim3(94, 32), 256, 0, stream>>>(h5, w6t, b6, out, low, 512);
}

// Round 9
// 351.351 us; speedup vs baseline: 2.7999x; 1.0841x over previous
//
#include <hip/hip_runtime.h>
#include <hip/hip_bf16.h>

typedef __attribute__((ext_vector_type(8))) short bf16x8;
typedef __attribute__((ext_vector_type(4))) float f32x4;
typedef __attribute__((ext_vector_type(8))) unsigned short u16x8;
typedef unsigned short ushort_t;
typedef unsigned int u32;

__device__ __forceinline__ ushort_t f2b(float f) {
    u32 u = __builtin_bit_cast(u32, f);
    u += 0x7FFFu + ((u >> 16) & 1u);
    return (ushort_t)(u >> 16);
}

__device__ __forceinline__ void gload_lds16(const void* g, void* l) {
    __builtin_amdgcn_global_load_lds(
        (const __attribute__((address_space(1))) u32*)g,
        (__attribute__((address_space(3))) u32*)l, 16, 0, 0);
}

// ---------------- prep: 6x transpose-cast W [K][N] f32 -> Wt [Npad][Kpad] bf16 --
struct TrDesc { const float* src; ushort_t* dst; int K, N, Kpad, Npad, base, nx; };
struct TrArgs { TrDesc d[6]; };

__global__ __launch_bounds__(256) void prep_kernel(TrArgs a) {
    __shared__ float T[64][65];
    const int bid = blockIdx.x, tid = threadIdx.x;
    int w = 0;
    #pragma unroll
    for (int i = 1; i < 6; ++i) if (bid >= a.d[i].base) w = i;
    const TrDesc d = a.d[w];
    const int local = bid - d.base;
    const int n0 = (local % d.nx) * 64, k0 = (local / d.nx) * 64;
    #pragma unroll
    for (int it = 0; it < 16; ++it) {
        int idx = it * 256 + tid;
        int r = idx >> 6, c = idx & 63;
        int k = k0 + r, n = n0 + c;
        T[c][r] = (k < d.K && n < d.N) ? d.src[(size_t)k * d.N + n] : 0.f;
    }
    __syncthreads();
    #pragma unroll
    for (int it = 0; it < 16; ++it) {
        int idx = it * 256 + tid;
        int r = idx >> 6, c = idx & 63;
        int n = n0 + r, k = k0 + c;
        if (k < d.Kpad)
            d.dst[(size_t)n * d.Kpad + k] = f2b(T[r][c]);
    }
}

// ---------------- fused L1..L5 chain (verified round 8, unchanged) --------------
__device__ __forceinline__ void layer_run(
    const char* actIn, char* actOut, char* Bsb,
    const ushort_t* __restrict__ Wt, const float* __restrict__ bias,
    int K, int N, bool relu, int tid)
{
    const int wave = tid >> 6, lane = tid & 63;
    const int l15 = lane & 15, g = lane >> 4;
    const int row_t = tid >> 2;
    const int sw_s = ((row_t >> 1) & 3) << 4;
    const int koff = ((((tid & 3) << 4)) ^ sw_s) >> 1;
    const int sxor = ((l15 >> 1) & 3) << 4;
    const int aRd = l15 * 64 + ((g * 16) ^ sxor);
    const int bRd = wave * 4096 + l15 * 64 + ((g * 16) ^ sxor);
    char* stW = Bsb + wave * 1024;
    const int nk = K >> 5;
    const int nmt = (N + 255) >> 8;

    for (int mt = 0; mt < nmt; ++mt) {
        const int ncols = N - mt * 256;
        const ushort_t* src0 = Wt + (size_t)(mt * 256 + row_t) * K + koff;
        f32x4 acc[4] = {};
        #pragma unroll
        for (int i = 0; i < 4; ++i)
            if (i * 64 < ncols) gload_lds16(src0 + (size_t)i * 64 * K, stW + i * 4096);
        __syncthreads();
        for (int kk = 0; kk < nk; ++kk) {
            const int cur = kk & 1, nxt = cur ^ 1;
            if (kk + 1 < nk) {
                #pragma unroll
                for (int i = 0; i < 4; ++i)
                    if (i * 64 < ncols)
                        gload_lds16(src0 + (size_t)i * 64 * K + (kk + 1) * 32,
                                    stW + nxt * 16384 + i * 4096);
            }
            bf16x8 af = *(const bf16x8*)(actIn + kk * 1024 + aRd);
            #pragma unroll
            for (int j = 0; j < 4; ++j) {
                bf16x8 bf = *(const bf16x8*)(Bsb + cur * 16384 + bRd + j * 1024);
                acc[j] = __builtin_amdgcn_mfma_f32_16x16x32_bf16(af, bf, acc[j], 0, 0, 0);
            }
            __syncthreads();
        }
        #pragma unroll
        for (int j = 0; j < 4; ++j) {
            int col = mt * 256 + wave * 64 + j * 16 + l15;
            if (col < N) {
                float bv = bias[col];
                #pragma unroll
                for (int r = 0; r < 4; ++r) {
                    float v = acc[j][r] + bv;
                    if (relu) v = fmaxf(v, 0.f);
                    int mrow = g * 4 + r;
                    int sw = ((mrow >> 1) & 3) << 4;
                    *(ushort_t*)(actOut + (col >> 5) * 1024 + mrow * 64 +
                                 ((2 * (col & 31)) ^ sw)) = f2b(v);
                }
            }
        }
    }
    __syncthreads();
}

struct ChainArgs {
    const float* low; const int* lbl; const float* emb;
    const ushort_t *w1t, *w2t, *w3t, *w4t, *w5t;
    const float *b1, *b2, *b3, *b4, *b5;
    ushort_t* h5;
};

__global__ __launch_bounds__(256) void chain_kernel(ChainArgs a) {
    __shared__ __align__(16) char smem[19456 + 16384 + 2 * 16384];
    char* act0 = smem;
    char* act1 = smem + 19456;
    char* Bsb  = smem + 19456 + 16384;
    const int tid = threadIdx.x;
    const int m0 = blockIdx.x << 4;

    for (int u = tid; u < 1216; u += 256) {
        int row = u / 76, c8 = u - row * 76;
        int sw = ((row >> 1) & 3) << 4;
        char* dst = act0 + (c8 >> 2) * 1024 + row * 64 + ((((c8 & 3) << 4)) ^ sw);
        u16x8 o;
        if (c8 < 75) {
            const float* sp = a.low + (size_t)(m0 + row) * 600 + c8 * 8;
            f32x4 v0 = *(const f32x4*)sp, v1 = *(const f32x4*)(sp + 4);
            #pragma unroll
            for (int j = 0; j < 4; ++j) { o[j] = f2b(v0[j]); o[4 + j] = f2b(v1[j]); }
        } else {
            #pragma unroll
            for (int j = 0; j < 8; ++j) o[j] = 0;
        }
        *(u16x8*)dst = o;
    }
    __syncthreads();

    layer_run(act0, act1, Bsb, a.w1t, a.b1, 608, 512, true,  tid);
    layer_run(act1, act0, Bsb, a.w2t, a.b2, 512, 256, true,  tid);
    layer_run(act0, act1, Bsb, a.w3t, a.b3, 256, 128, false, tid);

    for (int u = tid; u < 512; u += 256) {
        int row = u >> 5, c = u & 31;
        float v = c < 16 ? a.emb[(size_t)a.lbl[m0 + row] * 16 + c] : 0.f;
        int sw = ((row >> 1) & 3) << 4;
        *(ushort_t*)(act1 + 4096 + row * 64 + ((2 * c) ^ sw)) = f2b(v);
    }
    __syncthreads();

    layer_run(act1, act0, Bsb, a.w4t, a.b4, 160, 256, true, tid);
    layer_run(act0, act1, Bsb, a.w5t, a.b5, 256, 512, true, tid);

    for (int u = tid; u < 1024; u += 256) {
        int row = u >> 6, c8 = u & 63;
        int sw = ((row >> 1) & 3) << 4;
        u16x8 v = *(const u16x8*)(act1 + (c8 >> 2) * 1024 + row * 64 +
                                  (((c8 & 3) << 4) ^ sw));
        *(u16x8*)(a.h5 + (size_t)(m0 + row) * 512 + (c8 << 3)) = v;
    }
}

// ------------- L6: 128x128 dbuf GEMM + LDS-staged low window + XCD swizzle -----
__global__ __launch_bounds__(256, 3) void gemm128_l6(
    const ushort_t* __restrict__ A, const ushort_t* __restrict__ Bt,
    const float* __restrict__ bias, float* __restrict__ Cf,
    const float* __restrict__ low, int K)
{
    __shared__ ushort_t As[2][128 * 32];   // 8KB per buf
    __shared__ ushort_t Bs[2][128 * 32];
    __shared__ float lowS[128 * 32];       // 16KB: [row][32] f32 window
    const int tid = threadIdx.x;
    const int wave = tid >> 6, lane = tid & 63;
    const int l15 = lane & 15, g = lane >> 4;
    const int wr = wave >> 1, wc = wave & 1;

    // bijective XCD swizzle: xcd owns 4 m-panels x all 94 n-tiles; 4 consecutive
    // blocks share one w6t n-panel. 3008 = 8 xcd * (4 m * 94 n).
    const int bid = blockIdx.x;
    const int xcd = bid & 7, idx = bid >> 3;
    const int m0 = (xcd * 4 + (idx & 3)) * 128;
    const int n0 = (idx >> 2) * 128;

    // ---- low window staging: base_f = 16B-aligned start of the seg span ----
    const int tmin = n0 / 6;
    int smin = tmin / 20; if (smin > 98) smin = 98;
    int base_f = (smin * 6) & ~3; if (base_f > 568) base_f = 568;
    {
        // 16KB: 4 rounds x (256 lanes x 16B). byte p = q*4096 + tid*16.
        #pragma unroll
        for (int q = 0; q < 4; ++q) {
            int p = q * 4096 + tid * 16;
            int row = p >> 7, fidx = (p & 127) >> 2;
            gload_lds16(low + (size_t)(m0 + row) * 600 + base_f + fidx,
                        (char*)lowS + q * 4096 + wave * 1024);
        }
    }

    f32x4 acc[4][4] = {};

    const int p0 = tid * 16;
    const int row0 = p0 >> 6;
    const int k0s = (((p0 & 63) ^ (((row0 >> 1) & 3) << 4)) >> 1);
    const int p1 = 4096 + tid * 16;
    const int row1 = p1 >> 6;
    const int k1s = (((p1 & 63) ^ (((row1 >> 1) & 3) << 4)) >> 1);

    const ushort_t* a0 = A + (size_t)(m0 + row0) * K + k0s;
    const ushort_t* a1 = A + (size_t)(m0 + row1) * K + k1s;
    const ushort_t* b0 = Bt + (size_t)(n0 + row0) * K + k0s;
    const ushort_t* b1 = Bt + (size_t)(n0 + row1) * K + k1s;

    char* AsB = (char*)As + wave * 1024;
    char* BsB = (char*)Bs + wave * 1024;

    const int sxor = ((l15 >> 1) & 3) << 4;
    const ushort_t* ardA = &As[0][0] + (((wr * 64 + l15) * 64 + ((g * 16) ^ sxor)) >> 1);
    const ushort_t* brdB = &Bs[0][0] + (((wc * 64 + l15) * 64 + ((g * 16) ^ sxor)) >> 1);

    const int nk = K >> 5;   // 16
    gload_lds16(a0, AsB); gload_lds16(a1, AsB + 4096);
    gload_lds16(b0, BsB); gload_lds16(b1, BsB + 4096);
    a0 += 32; a1 += 32; b0 += 32; b1 += 32;
    __syncthreads();
    #pragma unroll 2
    for (int kk = 0; kk < nk; ++kk) {
        const int cur = kk & 1, nxt = cur ^ 1;
        if (kk + 1 < nk) {
            gload_lds16(a0, AsB + nxt * 8192);
            gload_lds16(a1, AsB + nxt * 8192 + 4096);
            gload_lds16(b0, BsB + nxt * 8192);
            gload_lds16(b1, BsB + nxt * 8192 + 4096);
            a0 += 32; a1 += 32; b0 += 32; b1 += 32;
        }
        bf16x8 af[4], bf[4];
        #pragma unroll
        for (int i = 0; i < 4; ++i) af[i] = *(const bf16x8*)(ardA + cur * 4096 + i * 512);
        #pragma unroll
        for (int j = 0; j < 4; ++j) bf[j] = *(const bf16x8*)(brdB + cur * 4096 + j * 512);
        #pragma unroll
        for (int i = 0; i < 4; ++i)
            #pragma unroll
            for (int j = 0; j < 4; ++j)
                acc[i][j] = __builtin_amdgcn_mfma_f32_16x16x32_bf16(af[i], bf[j], acc[i][j], 0, 0, 0);
        __syncthreads();
    }

    // epilogue: lin from LDS low-window; row outer, j inner (line-merged stores)
    float bvv[4]; int offv[4]; float alphav[4];
    bool anch[4], interi[4], valid[4];
    #pragma unroll
    for (int j = 0; j < 4; ++j) {
        int col = n0 + wc * 64 + j * 16 + l15;
        valid[j] = col < 12000;
        int cc = valid[j] ? col : 0;
        bvv[j] = bias[cc];
        int t = cc / 6, f = cc - t * 6;
        int seg = t / 20; if (seg > 98) seg = 98;
        offv[j] = seg * 6 + f - base_f;          // LDS-window-relative
        alphav[j] = (float)(t - seg * 20) * 0.05f;
        anch[j] = (t % 20) == 0;
        interi[j] = t < 1980;
    }
    const int colb = n0 + wc * 64 + l15;
    #pragma unroll
    for (int i = 0; i < 4; ++i)
        #pragma unroll
        for (int r = 0; r < 4; ++r) {
            const int row = m0 + wr * 64 + i * 16 + g * 4 + r;
            const float* lrow = lowS + (size_t)(row - m0) * 32;
            float* orow = Cf + (size_t)row * 12000;
            #pragma unroll
            for (int j = 0; j < 4; ++j) {
                if (!valid[j]) continue;
                float s = lrow[offv[j]], e = lrow[offv[j] + 6];
                float lin = (1.f - alphav[j]) * s + alphav[j] * e;
                float dec = acc[i][j][r] + bvv[j];
                float res = anch[j] ? lin : (interi[j] ? lin + 0.2f * (dec - lin) : dec);
                orow[colb + j * 16] = res;
            }
        }
}

extern "C" void kernel_launch(void* const* d_in, const int* in_sizes, int n_in,
                              void* d_out, int out_size, void* d_ws, size_t ws_size,
                              hipStream_t stream) {
    const float* low = (const float*)d_in[0];
    const int*   lbl = (const int*)d_in[1];
    const float* W1 = (const float*)d_in[2];  const float* b1 = (const float*)d_in[3];
    const float* W2 = (const float*)d_in[4];  const float* b2 = (const float*)d_in[5];
    const float* W3 = (const float*)d_in[6];  const float* b3 = (const float*)d_in[7];
    const float* W4 = (const float*)d_in[8];  const float* b4 = (const float*)d_in[9];
    const float* W5 = (const float*)d_in[10]; const float* b5 = (const float*)d_in[11];
    const float* W6 = (const float*)d_in[12]; const float* b6 = (const float*)d_in[13];
    const float* emb = (const float*)d_in[14];
    float* out = (float*)d_out;

    char* ws = (char*)d_ws;
    size_t off = 0;
    auto alloc = [&](size_t elems) {
        ushort_t* p = (ushort_t*)(ws + off);
        off = (off + elems * 2 + 255) & ~(size_t)255;
        return p;
    };
    ushort_t* w1t = alloc((size_t)512 * 608);
    ushort_t* w2t = alloc((size_t)256 * 512);
    ushort_t* w3t = alloc((size_t)128 * 256);
    ushort_t* w4t = alloc((size_t)256 * 160);
    ushort_t* w5t = alloc((size_t)512 * 256);
    ushort_t* w6t = alloc((size_t)12032 * 512);
    ushort_t* h5  = alloc((size_t)4096 * 512);

    TrArgs ta;
    int base = 0;
    auto mk = [&](int i, const float* s, ushort_t* d, int K, int N, int Kp, int Np) {
        int nx = Np / 64, ny = (Kp + 63) / 64;
        ta.d[i] = TrDesc{s, d, K, N, Kp, Np, base, nx};
        base += nx * ny;
    };
    mk(0, W1, w1t, 600, 512, 608, 512);
    mk(1, W2, w2t, 512, 256, 512, 256);
    mk(2, W3, w3t, 256, 128, 256, 128);
    mk(3, W4, w4t, 144, 256, 160, 256);
    mk(4, W5, w5t, 256, 512, 256, 512);
    mk(5, W6, w6t, 512, 12000, 512, 12032);

    prep_kernel<<<dim3(base), 256, 0, stream>>>(ta);

    ChainArgs ca;
    ca.low = low; ca.lbl = lbl; ca.emb = emb;
    ca.w1t = w1t; ca.w2t = w2t; ca.w3t = w3t; ca.w4t = w4t; ca.w5t = w5t;
    ca.b1 = b1; ca.b2 = b2; ca.b3 = b3; ca.b4 = b4; ca.b5 = b5;
    ca.h5 = h5;
    chain_kernel<<<dim3(256), 256, 0, stream>>>(ca);

    // L6: h5(512) @ w6t + fused interp/blend -> out f32   [3008 blocks, XCD swz]
    gemm128_l6<<<dim3(3008), 256, 0, stream>>>(h5, w6t, b6, out, low, 512);
}